// Round 16
// baseline (279.303 us; speedup 1.0000x reference)
//
#include <hip/hip_runtime.h>
#include <hip/hip_bf16.h>
#include <stdint.h>

// ChebyKAN: y[b,o] = sum_{i,d} T_d(tanh(x[b,i])) * c[i,o,d]
//   == GEMM [16384 x 4096] x [4096 x 512]  (d=1..8; d=0 via column-sum)
//
// R14: ZERO-SYNC design. Eight structural variants of the 2-phase
// barrier-locked loop all landed 94-115us with every pipe <=43% (the m233
// stall signature). This kernel removes the mechanism: fully independent
// waves (one 32x64 output tile each, 4096 waves), NO LDS, NO barriers, no
// waitcnt asm. B (4MB bf16, reordered flat in ws, L2-resident) is loaded
// per-fragment via global_load_dwordx4 into registers, double-buffered one
// K-step (~500cy) ahead of use -- covers L2 latency per-wave. A via R13's
// in-place Chebyshev pipeline (afC packed one step early, GENs scheduled
// under MFMA clusters). Per-wave ordering only => race-free by construction.

#define IN_DIM 512
#define OUT_DIM 512

typedef __attribute__((ext_vector_type(8))) short short8;
typedef __attribute__((ext_vector_type(4))) float f32x4;

__device__ __forceinline__ unsigned short f2bf(float f) {
  __hip_bfloat16 h = __float2bfloat16(f);
  return __builtin_bit_cast(unsigned short, h);
}

__device__ __forceinline__ float fast_tanh(float v) {
  float e = __expf(v + v);
  return 1.0f - 2.0f * __builtin_amdgcn_rcpf(e + 1.0f);
}

// ---------------------------------------------------------------------------
// Kernel 1: coeffs[i][o][d] (f32) -> ws: flat bf16 B chunks, NO swizzle.
// Chunk s = it*4 + p (64KB): byte = s*65536 + o*128 + dl*64 + il*2 holds
// coeff d = 1 + 2p + dl for column o, i = it*32 + il.
// ---------------------------------------------------------------------------
__global__ __launch_bounds__(256) void cheby_reorder_b(
    const float* __restrict__ coeffs, unsigned char* __restrict__ bws) {
  const int g = blockIdx.x * 256 + threadIdx.x;  // 512*512 threads
  const int i = g & 511;
  const int o = g >> 9;
  const int it = i >> 5, il = i & 31;
  const float* cp = coeffs + (size_t)i * 4608 + (size_t)o * 9;
#pragma unroll
  for (int p = 0; p < 4; ++p) {
    unsigned char* base =
        bws + (((size_t)(it * 4 + p)) << 16) + (size_t)o * 128 + il * 2;
    *(unsigned short*)(base) = f2bf(cp[1 + 2 * p]);       // dl=0: d=1+2p
    *(unsigned short*)(base + 64) = f2bf(cp[2 + 2 * p]);  // dl=1: d=2+2p
  }
}

// ---------------------------------------------------------------------------
// Kernel 2: colsum[o] = sum_i coeffs[i][o][0]   (T_0 == 1 contribution)
// ---------------------------------------------------------------------------
__global__ __launch_bounds__(64) void cheby_colsum(
    const float* __restrict__ coeffs, float* __restrict__ cs) {
  const int o = blockIdx.x;
  const int l = threadIdx.x;
  float s = 0.0f;
#pragma unroll
  for (int j = 0; j < 8; ++j)
    s += coeffs[(size_t)(l + j * 64) * 4608 + (size_t)o * 9];
#pragma unroll
  for (int off = 32; off > 0; off >>= 1) s += __shfl_down(s, off, 64);
  if (l == 0) cs[o] = s;
}

// ---------------------------------------------------------------------------
// Kernel 3: fused basis-gen + bf16 MFMA GEMM. Independent 32x64 waves.
// ---------------------------------------------------------------------------
// issue next step's 8 B-fragment loads into BUF (plain loads; used next step)
#define ISSUE_BF(S, BUF)                                                   \
  {                                                                        \
    const unsigned char* bs = bbase + ((size_t)(S) << 16);                 \
    _Pragma("unroll") for (int fn = 0; fn < 4; ++fn)                       \
        _Pragma("unroll") for (int ks = 0; ks < 2; ++ks)                   \
            BUF[fn][ks] =                                                  \
                *(const short8*)(bs + fn * 2048 + ks * 64);                \
  }

// 8 MFMAs: slice KS of buffer BUF against fragment AF
#define MFMA8(AF, BUF, KS)                                                 \
  {                                                                        \
    _Pragma("unroll") for (int fn = 0; fn < 4; ++fn)                       \
        _Pragma("unroll") for (int fm = 0; fm < 2; ++fm)                   \
            acc[fm][fn] = __builtin_amdgcn_mfma_f32_16x16x32_bf16(         \
                AF[fm], BUF[fn][KS], acc[fm][fn], 0, 0, 0);                \
  }

// GEN_A: Tpp <- fma(t2,Tp,-Tpp) (next even degree), pack -> af1
#define GEN_A()                                                            \
  {                                                                        \
    _Pragma("unroll") for (int fm = 0; fm < 2; ++fm)                       \
        _Pragma("unroll") for (int j = 0; j < 8; ++j) {                    \
      Tpp[fm][j] = __builtin_fmaf(t2[fm][j], Tp[fm][j], -Tpp[fm][j]);      \
      af1[fm][j] = (short)f2bf(Tpp[fm][j]);                                \
    }                                                                      \
  }

// GEN_B: Tp <- fma(t2,Tpp,-Tp) (next odd degree), pack -> afC (next step d0)
#define GEN_B()                                                            \
  {                                                                        \
    _Pragma("unroll") for (int fm = 0; fm < 2; ++fm)                       \
        _Pragma("unroll") for (int j = 0; j < 8; ++j) {                    \
      Tp[fm][j] = __builtin_fmaf(t2[fm][j], Tpp[fm][j], -Tp[fm][j]);       \
      afC[fm][j] = (short)f2bf(Tp[fm][j]);                                 \
    }                                                                      \
  }

// INIT from xv: Tp=T1=tanh, Tpp=T0=1, pack T1 -> afC (next step d0)
#define INIT_()                                                            \
  {                                                                        \
    _Pragma("unroll") for (int fm = 0; fm < 2; ++fm)                       \
        _Pragma("unroll") for (int j = 0; j < 8; ++j) {                    \
      const float xval = ((const float*)&xv[fm][j >> 2])[j & 3];           \
      const float th = fast_tanh(xval);                                    \
      t2[fm][j] = th + th;                                                 \
      Tp[fm][j] = th;                                                      \
      Tpp[fm][j] = 1.0f;                                                   \
      afC[fm][j] = (short)f2bf(th);                                        \
    }                                                                      \
  }

#define LOAD_X(IT)                                                         \
  {                                                                        \
    xv[0][0] = reinterpret_cast<const float4*>(xr0 + (IT) * 32)[0];        \
    xv[0][1] = reinterpret_cast<const float4*>(xr0 + (IT) * 32)[1];        \
    xv[1][0] = reinterpret_cast<const float4*>(xr1 + (IT) * 32)[0];        \
    xv[1][1] = reinterpret_cast<const float4*>(xr1 + (IT) * 32)[1];        \
  }

// one K-step. Q static 0..3 (degree pair), BUFC current regs, BUFN prefetch.
#define STEP(IT, Q, BUFC, BUFN)                                            \
  {                                                                        \
    const int s_ = (IT) * 4 + (Q);                                         \
    if ((Q) == 2) LOAD_X(((IT) < 15) ? (IT) + 1 : 15);                     \
    ISSUE_BF((s_ < 63) ? s_ + 1 : 63, BUFN);                               \
    __builtin_amdgcn_sched_barrier(0);                                     \
    MFMA8(afC, BUFC, 0);  /* consumes T_{1+2Q} */                          \
    GEN_A();              /* -> T_{2+2Q} in af1 */                         \
    MFMA8(af1, BUFC, 1);  /* consumes T_{2+2Q} */                          \
    if ((Q) == 3) { INIT_(); } else { GEN_B(); } /* -> next d0 in afC */   \
  }

__global__ __launch_bounds__(256, 2) void cheby_gemm(
    const float* __restrict__ x, const unsigned char* __restrict__ bws,
    const float* __restrict__ colsum, float* __restrict__ out) {
  const int gwid = blockIdx.x * 4 + (threadIdx.x >> 6);  // 0..4095
  const int lane = threadIdx.x & 63;
  const int l15 = lane & 15;
  const int lhi = lane >> 4;
  const int nblk = gwid >> 9;          // 0..7  (512 consecutive waves share B)
  const int m0 = (gwid & 511) * 32;
  const int n0 = nblk * 64;

  // per-lane A ownership: rows m0 + fm*16 + l15 (fm=0..1), i = it*32+lhi*8+j
  const float* xr0 = x + (size_t)(m0 + l15) * IN_DIM + lhi * 8;
  const float* xr1 = xr0 + (size_t)16 * IN_DIM;
  // per-lane B base: col n0+l15, k-quarter lhi
  const unsigned char* bbase =
      bws + (size_t)(n0 + l15) * 128 + lhi * 16;

  float t2[2][8], Tp[2][8], Tpp[2][8];
  short8 afC[2], af1[2];
  short8 bfE[4][2], bfO[4][2];
  float4 xv[2][2];
  f32x4 acc[2][4];
#pragma unroll
  for (int a = 0; a < 2; ++a)
#pragma unroll
    for (int b = 0; b < 4; ++b) acc[a][b] = (f32x4){0.f, 0.f, 0.f, 0.f};

  // ---- prologue: x(it0), B(step0) -> bfE, afC = T1
  LOAD_X(0);
  ISSUE_BF(0, bfE);
  INIT_();

  for (int it = 0; it < 16; ++it) {
    STEP(it, 0, bfE, bfO);
    STEP(it, 1, bfO, bfE);
    STEP(it, 2, bfE, bfO);
    STEP(it, 3, bfO, bfE);
  }

  // ---- epilogue: add d=0 colsum, store f32
  float csv[4];
#pragma unroll
  for (int fn = 0; fn < 4; ++fn) csv[fn] = colsum[n0 + fn * 16 + l15];
  const int lhi4 = lhi * 4;
#pragma unroll
  for (int fm = 0; fm < 2; ++fm) {
    const int r0 = m0 + fm * 16 + lhi4;
#pragma unroll
    for (int fn = 0; fn < 4; ++fn) {
      const int col = n0 + fn * 16 + l15;
#pragma unroll
      for (int r = 0; r < 4; ++r)
        out[(size_t)(r0 + r) * OUT_DIM + col] = acc[fm][fn][r] + csv[fn];
    }
  }
}

extern "C" void kernel_launch(void* const* d_in, const int* in_sizes, int n_in,
                              void* d_out, int out_size, void* d_ws,
                              size_t ws_size, hipStream_t stream) {
  const float* x = (const float*)d_in[0];           // [16384, 512] f32
  const float* coeffs = (const float*)d_in[1];      // [512, 512, 9] f32
  float* out = (float*)d_out;                       // [16384, 512] f32
  unsigned char* bws = (unsigned char*)d_ws;        // 4MB bf16 B chunks
  float* cs = (float*)((unsigned char*)d_ws + ((size_t)4 << 20));  // +2KB

  hipLaunchKernelGGL(cheby_reorder_b, dim3(1024), dim3(256), 0, stream, coeffs,
                     bws);
  hipLaunchKernelGGL(cheby_colsum, dim3(512), dim3(64), 0, stream, coeffs, cs);
  hipLaunchKernelGGL(cheby_gemm, dim3(1024), dim3(256), 0, stream, x, bws, cs,
                     out);
}